// Round 15
// baseline (261.417 us; speedup 1.0000x reference)
//
#include <hip/hip_runtime.h>
#include <hip/hip_bf16.h>

typedef __bf16 bf16_t;
typedef __bf16 bf16x8 __attribute__((ext_vector_type(8)));
typedef float f32x16 __attribute__((ext_vector_type(16)));

#define B_ 8
#define LQ_ 2048
#define LK_ 2048
#define DM_ 1024

__device__ __forceinline__ void gload16(const void* g, void* l) {
  __builtin_amdgcn_global_load_lds(
      (const __attribute__((address_space(1))) void*)g,
      (__attribute__((address_space(3))) void*)l, 16, 0, 0);
}

// ------------- fused prep: x/keys/Wq f32->bf16 + V transpose -------------
__global__ __launch_bounds__(256) void prep_kernel(
    const float* __restrict__ x, const float* __restrict__ keys,
    const float* __restrict__ Wq, const float* __restrict__ vals,
    bf16_t* __restrict__ xbf, bf16_t* __restrict__ kbf,
    bf16_t* __restrict__ wqbf, bf16_t* __restrict__ vt) {
  const int bid = blockIdx.x;
  const int tid = threadIdx.x;
  if (bid < 2176) {
    const float* in;
    bf16_t* out;
    int n8, i0, nb;
    if (bid < 1024) {
      in = x; out = xbf; n8 = (B_ * LQ_ * DM_) / 8; i0 = bid; nb = 1024;
    } else if (bid < 2048) {
      in = keys; out = kbf; n8 = (B_ * LK_ * DM_) / 8; i0 = bid - 1024; nb = 1024;
    } else {
      in = Wq; out = wqbf; n8 = (DM_ * DM_) / 8; i0 = bid - 2048; nb = 128;
    }
    int stride = nb * 256;
    for (int i = i0 * 256 + tid; i < n8; i += stride) {
      const float4* p = reinterpret_cast<const float4*>(in) + (size_t)i * 2;
      float4 a = p[0], b = p[1];
      bf16x8 o;
      o[0] = (bf16_t)a.x; o[1] = (bf16_t)a.y; o[2] = (bf16_t)a.z; o[3] = (bf16_t)a.w;
      o[4] = (bf16_t)b.x; o[5] = (bf16_t)b.y; o[6] = (bf16_t)b.z; o[7] = (bf16_t)b.w;
      *reinterpret_cast<bf16x8*>(out + (size_t)i * 8) = o;
    }
  } else {
    __shared__ bf16_t tile[64][65];
    const int t = bid - 2176;            // 0..4095
    const int k0 = (t & 31) * 64;
    const int d0 = ((t >> 5) & 15) * 64;
    const int b = t >> 9;
    const float* src = vals + ((size_t)b * LK_ + k0) * DM_ + d0;
    const int lr = tid >> 4;
    const int lc = (tid & 15) * 4;
#pragma unroll
    for (int rr = 0; rr < 64; rr += 16) {
      float4 v = *reinterpret_cast<const float4*>(src + (size_t)(rr + lr) * DM_ + lc);
      bf16_t* d = &tile[rr + lr][lc];
      d[0] = (bf16_t)v.x; d[1] = (bf16_t)v.y; d[2] = (bf16_t)v.z; d[3] = (bf16_t)v.w;
    }
    __syncthreads();
    bf16_t* dst = vt + ((size_t)b * DM_ + d0) * LK_ + k0;
    const int sd = tid >> 3;
    const int sk = (tid & 7) * 8;
#pragma unroll
    for (int pass = 0; pass < 2; ++pass) {
      const int d = pass * 32 + sd;
      bf16x8 o;
#pragma unroll
      for (int j = 0; j < 8; ++j) o[j] = tile[sk + j][d];
      *reinterpret_cast<bf16x8*>(dst + (size_t)d * LK_ + sk) = o;
    }
  }
}

// ---------------- rowsum partials -> inverse rowsums ----------------
__global__ __launch_bounds__(256) void rowsum_inv_kernel(
    const float* __restrict__ pbuf, float* __restrict__ rinv) {
  int R = blockIdx.x * 256 + threadIdx.x;  // 0..16383
  int b = R >> 11, row = R & 2047;
  float s = 0.f;
#pragma unroll
  for (int cb = 0; cb < 8; ++cb)
    s += pbuf[((long)b * 8 + cb) * 2048 + row];
  rinv[R] = 1.0f / s;
}

// ------------ 256x256 8-phase GEMM, C = A * B^T, 32x32x16 MFMA ------------
// r8's verified sync skeleton (drain-before-barrier, read-after-barrier,
// identical staging slots + vmcnt(4)@P4/P8) with the MFMA shape switched
// 16x16x32 -> 32x32x16: HALF the MFMA instructions (8/phase/wave), higher
// ceiling shape (2382 vs 2075 TF ubench). Fragment geometry re-derived:
//   A/B operand: row/col = lane&31, k = (lane>>5)*8 + j (8 bf16, b128 read)
//   swizzle (involution): phys_granule = logical ^ (row&7), 8x16B granules
//     -> read: 8 lanes per granule-column = 2/bank (free)
//     -> stage: source col granule = (tid&7) ^ ((tid>>3)&7), row+64 invariant
//   C/D: col = lane&31, row = (reg&3) + 8*(reg>>2) + 4*(lane>>5)  [m74/m101]
// MODE 0: C bf16, C += bias[col]                    (Q projection)
// MODE 1: C bf16, C = exp(C/32 + mask[b][col]); + rowsum partials->extra2
// MODE 2: C f32,  C = acc * rinv[b][row]            (extra = rinv)
#define BARX __builtin_amdgcn_s_barrier()
#define PRIO1 __builtin_amdgcn_s_setprio(1)
#define PRIO0 __builtin_amdgcn_s_setprio(0)

#define RD_A2(MT, DOFF)                                                       \
  _Pragma("unroll") for (int ks = 0; ks < 4; ++ks) {                          \
    aF[0][ks] = *(const bf16x8*)(paks[ks] + (DOFF) + (MT) * 4096);            \
    aF[1][ks] = *(const bf16x8*)(paks[ks] + (DOFF) + ((MT) + 1) * 4096);      \
  }
#define RD_B(NT, DOFF, BF)                                                    \
  _Pragma("unroll") for (int ks = 0; ks < 4; ++ks)                            \
    BF[ks] = *(const bf16x8*)(pbks[ks] + (DOFF) + (NT) * 4096);
#define MQ8(MB, BF, NT)                                                       \
  _Pragma("unroll") for (int ks = 0; ks < 4; ++ks)                            \
  _Pragma("unroll") for (int m2 = 0; m2 < 2; ++m2)                            \
    acc[(MB) + m2][NT] = __builtin_amdgcn_mfma_f32_32x32x16_bf16(             \
        aF[m2][ks], BF[ks], acc[(MB) + m2][NT], 0, 0, 0);

template <int MODE>
__global__ __launch_bounds__(512, 1) void gemm_bt(
    const bf16_t* __restrict__ A, const bf16_t* __restrict__ Bm,
    void* __restrict__ Cv, const float* __restrict__ extra,
    float* __restrict__ extra2,
    int N, int K, long sA, long sB, long sC, long sE, int gxs, int gys) {
  __shared__ bf16_t lds[65536];  // A: d0 [0,32KB) d1 [32,64KB); B: [64,128KB)

  const int tid = threadIdx.x;
  const int lane = tid & 63;
  const int wave = tid >> 6;

  // XCD-aware bijective block swizzle (gridDim.x % 8 == 0 for all our grids)
  const int nwg = gridDim.x;
  const int lin = blockIdx.x;
  const int cpx = nwg >> 3;
  const int swz = (lin & 7) * cpx + (lin >> 3);
  const int gx = 1 << gxs;
  const int bx = swz & (gx - 1);
  const int rem = swz >> gxs;
  const int by = rem & ((1 << gys) - 1);
  const int bz = rem >> gys;

  const bf16_t* Ab = A + (long)bz * sA + (long)(by * 256) * K;
  const bf16_t* Bb = Bm + (long)bz * sB + (long)(bx * 256) * K;

  // staging geometry: chunk = tid; row = tid>>3, phys granule = tid&7,
  // source col granule pre-swizzled by row&7.
  const int r0 = tid >> 3;                              // 0..63
  const int scol = ((tid & 7) ^ (r0 & 7)) * 8;          // pre-swizzled col

  auto STG = [&](const bf16_t* Mb, int d, int mat, int h, int t) {
    const bf16_t* g = Mb + (long)(h * 128 + r0) * K + t * 64 + scol;
    bf16_t* l = lds + mat * 32768 + d * 16384 + h * 8192 + wave * 512;
    gload16(g, l);
    gload16(g + (long)64 * K, l + 4096);   // row+64: (r&7) unchanged
  };

  // fragment read geometry (32x32x16)
  const int wr = wave >> 2;   // 0..1
  const int wc = wave & 3;    // 0..3
  const int l31 = lane & 31;
  const int g = lane >> 5;    // k-group 0/1
  const int q = lane & 7;
  const char* ldsc = (const char*)lds;
  const char* paks[4];
  const char* pbks[4];
#pragma unroll
  for (int ks = 0; ks < 4; ++ks) {
    const int ga = ((ks * 2 + g) ^ q) * 16;   // phys granule bytes
    paks[ks] = ldsc + (wr * 128 + l31) * 128 + ga;
    pbks[ks] = ldsc + 65536 + (wc * 64 + l31) * 128 + ga;
  }

  f32x16 acc[4][2] = {};
  bf16x8 aF[2][4], bF0[4], bF1[4];

  const int NT2 = K >> 7;  // iterations, 2 K-tiles (BK=64) each

  // prologue: t0 full (8 loads) + t1 B h0,h1 (4 loads)
  STG(Ab, 0, 0, 0, 0); STG(Ab, 0, 0, 1, 0);
  STG(Bb, 0, 1, 0, 0); STG(Bb, 0, 1, 1, 0);
  STG(Bb, 1, 1, 0, 1); STG(Bb, 1, 1, 1, 1);
  asm volatile("s_waitcnt vmcnt(4)" ::: "memory");  // t0 complete
  BARX;

  for (int j = 0; j < NT2; ++j) {
    const bool nl = (j + 1 < NT2);
    const int t1 = 2 * j + 1, t2 = 2 * j + 2, t3 = 2 * j + 3;
    // ---- P1: (m01, n0) of dbuf0 ----
    RD_A2(0, 0); RD_B(0, 0, bF0);
    STG(Ab, 1, 0, 0, t1);
    BARX; PRIO1; MQ8(0, bF0, 0); PRIO0; BARX;
    // ---- P2: (m01, n1) ----
    RD_B(1, 0, bF1);
    STG(Ab, 1, 0, 1, t1);
    BARX; PRIO1; MQ8(0, bF1, 1); PRIO0; BARX;
    // ---- P3: (m23, n1) ----
    RD_A2(2, 0);
    if (nl) STG(Bb, 0, 1, 0, t2);
    BARX; PRIO1; MQ8(2, bF1, 1); PRIO0; BARX;
    // ---- P4: (m23, n0); dbuf1 complete after this phase ----
    if (nl) STG(Bb, 0, 1, 1, t2);
    BARX; PRIO1; MQ8(2, bF0, 0); PRIO0;
    if (nl) { asm volatile("s_waitcnt vmcnt(4)" ::: "memory"); }
    else    { asm volatile("s_waitcnt vmcnt(0)" ::: "memory"); }
    BARX;
    // ---- P5: (m01, n0) of dbuf1 ----
    RD_A2(0, 32768); RD_B(0, 32768, bF0);
    if (nl) STG(Ab, 0, 0, 0, t2);
    BARX; PRIO1; MQ8(0, bF0, 0); PRIO0; BARX;
    // ---- P6: (m01, n1) ----
    RD_B(1, 32768, bF1);
    if (nl) STG(Ab, 0, 0, 1, t2);
    BARX; PRIO1; MQ8(0, bF1, 1); PRIO0; BARX;
    // ---- P7: (m23, n1) ----
    RD_A2(2, 32768);
    if (nl) STG(Bb, 1, 1, 0, t3);
    BARX; PRIO1; MQ8(2, bF1, 1); PRIO0; BARX;
    // ---- P8: (m23, n0); dbuf0 complete after this phase ----
    if (nl) STG(Bb, 1, 1, 1, t3);
    BARX; PRIO1; MQ8(2, bF0, 0); PRIO0;
    if (nl) { asm volatile("s_waitcnt vmcnt(4)" ::: "memory"); }
    BARX;
  }
  // loop exits with vmcnt==0 and all LDS reads complete -> LDS reusable.

  // epilogue (32x32 C/D layout)
  const int col0 = bx * 256 + wc * 64;
  const int row0 = by * 256 + wr * 128;

  if (MODE == 0) {
    bf16_t* C = (bf16_t*)Cv;
#pragma unroll
    for (int mt = 0; mt < 4; ++mt)
#pragma unroll
      for (int nt = 0; nt < 2; ++nt) {
        const int col = col0 + nt * 32 + l31;
        float bias = extra[col];
#pragma unroll
        for (int reg = 0; reg < 16; ++reg) {
          int row = row0 + mt * 32 + (reg & 3) + 8 * (reg >> 2) + 4 * g;
          C[(long)row * N + col] = (bf16_t)(acc[mt][nt][reg] + bias);
        }
      }
  } else if (MODE == 1) {
    bf16_t* C = (bf16_t*)Cv + (long)bz * sC;
    float* lds_f = (float*)lds;  // [wc][256 block-rows]
#pragma unroll
    for (int mt = 0; mt < 4; ++mt) {
      float s16[16];
#pragma unroll
      for (int r = 0; r < 16; ++r) s16[r] = 0.f;
#pragma unroll
      for (int nt = 0; nt < 2; ++nt) {
        const int col = col0 + nt * 32 + l31;
        float mk = extra[(long)bz * sE + col];
#pragma unroll
        for (int reg = 0; reg < 16; ++reg) {
          int row = row0 + mt * 32 + (reg & 3) + 8 * (reg >> 2) + 4 * g;
          float e = __expf(acc[mt][nt][reg] * 0.03125f + mk);
          C[(long)row * N + col] = (bf16_t)e;
          s16[reg] += e;
        }
      }
      // column-reduce over the 32 lanes of this half (xor<32 stays in-half)
#pragma unroll
      for (int reg = 0; reg < 16; ++reg) {
#pragma unroll
        for (int w = 1; w < 32; w <<= 1)
          s16[reg] += __shfl_xor(s16[reg], w, 64);
      }
      if (l31 == 0) {
#pragma unroll
        for (int reg = 0; reg < 16; ++reg) {
          int rl = (reg & 3) + 8 * (reg >> 2) + 4 * g;
          lds_f[wc * 256 + wr * 128 + mt * 32 + rl] = s16[reg];
        }
      }
    }
    __syncthreads();
    if (tid < 256) {
      float s4 = lds_f[tid] + lds_f[256 + tid] + lds_f[512 + tid] +
                 lds_f[768 + tid];
      extra2[((long)bz * 8 + bx) * 2048 + by * 256 + tid] = s4;
    }
  } else {
    float* C = (float*)Cv + (long)bz * sC;
    const float* rinv = extra + (long)bz * 2048;
#pragma unroll
    for (int mt = 0; mt < 4; ++mt)
#pragma unroll
      for (int reg = 0; reg < 16; ++reg) {
        int row = row0 + mt * 32 + (reg & 3) + 8 * (reg >> 2) + 4 * g;
        float iv = rinv[row];
#pragma unroll
        for (int nt = 0; nt < 2; ++nt) {
          const int col = col0 + nt * 32 + l31;
          C[(long)row * N + col] = acc[mt][nt][reg] * iv;
        }
      }
  }
}

extern "C" void kernel_launch(void* const* d_in, const int* in_sizes, int n_in,
                              void* d_out, int out_size, void* d_ws, size_t ws_size,
                              hipStream_t stream) {
  const float* x    = (const float*)d_in[0];
  const float* mask = (const float*)d_in[1];
  const float* keys = (const float*)d_in[2];
  const float* vals = (const float*)d_in[3];
  const float* Wq   = (const float*)d_in[4];
  const float* bq   = (const float*)d_in[5];
  float* out = (float*)d_out;

  char* ws = (char*)d_ws;
  bf16_t* kbf    = (bf16_t*)(ws);
  bf16_t* vt     = (bf16_t*)(ws + 33554432);
  bf16_t* qbf    = (bf16_t*)(ws + 67108864);
  bf16_t* logits = (bf16_t*)(ws + 100663296);  // holds p_unnorm = exp(logit)
  bf16_t* xbf    = logits;  // reused: x_bf dead before logits are written
  bf16_t* wqbf   = (bf16_t*)(ws + 167772160);
  float* pbuf = (float*)(ws + 167772160);            // [8][8][2048] partials
  float* rinv = (float*)(ws + 167772160 + 524288);   // [8][2048] 1/rowsum

  // 1. fused prep: converts + V transpose
  prep_kernel<<<6272, 256, 0, stream>>>(x, keys, Wq, vals, xbf, kbf, wqbf, vt);

  // 2. Q = x @ Wq^T + bq   (M=16384, N=1024, K=1024) grid 4x64 = 256
  gemm_bt<0><<<256, 512, 0, stream>>>(
      xbf, wqbf, qbf, bq, nullptr, DM_, DM_, 0, 0, 0, 0, 2, 6);

  // 3. p_unnorm = exp(Q @ K^T / 32 + mask), + rowsum partials
  gemm_bt<1><<<512, 512, 0, stream>>>(
      qbf, kbf, logits, mask, pbuf, LK_, DM_,
      (long)LQ_ * DM_, (long)LK_ * DM_, (long)LQ_ * LK_, LK_, 3, 3);

  // 4. rinv = 1 / rowsum
  rowsum_inv_kernel<<<64, 256, 0, stream>>>(pbuf, rinv);

  // 5. out = (P @ Vt^T) * rinv[row]  (per batch M=2048, N=1024, K=2048)
  gemm_bt<2><<<256, 512, 0, stream>>>(
      logits, vt, out, rinv, nullptr, DM_, LK_,
      (long)LQ_ * LK_, (long)DM_ * LK_, (long)LQ_ * DM_, 0, 2, 3);
}

// Round 16
// 260.729 us; speedup vs baseline: 1.0026x; 1.0026x over previous
//
#include <hip/hip_runtime.h>
#include <hip/hip_bf16.h>

typedef __bf16 bf16_t;
typedef __bf16 bf16x8 __attribute__((ext_vector_type(8)));
typedef float f32x16 __attribute__((ext_vector_type(16)));

#define B_ 8
#define LQ_ 2048
#define LK_ 2048
#define DM_ 1024

__device__ __forceinline__ void gload16(const void* g, void* l) {
  __builtin_amdgcn_global_load_lds(
      (const __attribute__((address_space(1))) void*)g,
      (__attribute__((address_space(3))) void*)l, 16, 0, 0);
}

// ------------- fused prep: x/keys/Wq f32->bf16 + V transpose -------------
__global__ __launch_bounds__(256) void prep_kernel(
    const float* __restrict__ x, const float* __restrict__ keys,
    const float* __restrict__ Wq, const float* __restrict__ vals,
    bf16_t* __restrict__ xbf, bf16_t* __restrict__ kbf,
    bf16_t* __restrict__ wqbf, bf16_t* __restrict__ vt) {
  const int bid = blockIdx.x;
  const int tid = threadIdx.x;
  if (bid < 2176) {
    const float* in;
    bf16_t* out;
    int n8, i0, nb;
    if (bid < 1024) {
      in = x; out = xbf; n8 = (B_ * LQ_ * DM_) / 8; i0 = bid; nb = 1024;
    } else if (bid < 2048) {
      in = keys; out = kbf; n8 = (B_ * LK_ * DM_) / 8; i0 = bid - 1024; nb = 1024;
    } else {
      in = Wq; out = wqbf; n8 = (DM_ * DM_) / 8; i0 = bid - 2048; nb = 128;
    }
    int stride = nb * 256;
    for (int i = i0 * 256 + tid; i < n8; i += stride) {
      const float4* p = reinterpret_cast<const float4*>(in) + (size_t)i * 2;
      float4 a = p[0], b = p[1];
      bf16x8 o;
      o[0] = (bf16_t)a.x; o[1] = (bf16_t)a.y; o[2] = (bf16_t)a.z; o[3] = (bf16_t)a.w;
      o[4] = (bf16_t)b.x; o[5] = (bf16_t)b.y; o[6] = (bf16_t)b.z; o[7] = (bf16_t)b.w;
      *reinterpret_cast<bf16x8*>(out + (size_t)i * 8) = o;
    }
  } else {
    __shared__ bf16_t tile[64][65];
    const int t = bid - 2176;            // 0..4095
    const int k0 = (t & 31) * 64;
    const int d0 = ((t >> 5) & 15) * 64;
    const int b = t >> 9;
    const float* src = vals + ((size_t)b * LK_ + k0) * DM_ + d0;
    const int lr = tid >> 4;
    const int lc = (tid & 15) * 4;
#pragma unroll
    for (int rr = 0; rr < 64; rr += 16) {
      float4 v = *reinterpret_cast<const float4*>(src + (size_t)(rr + lr) * DM_ + lc);
      bf16_t* d = &tile[rr + lr][lc];
      d[0] = (bf16_t)v.x; d[1] = (bf16_t)v.y; d[2] = (bf16_t)v.z; d[3] = (bf16_t)v.w;
    }
    __syncthreads();
    bf16_t* dst = vt + ((size_t)b * DM_ + d0) * LK_ + k0;
    const int sd = tid >> 3;
    const int sk = (tid & 7) * 8;
#pragma unroll
    for (int pass = 0; pass < 2; ++pass) {
      const int d = pass * 32 + sd;
      bf16x8 o;
#pragma unroll
      for (int j = 0; j < 8; ++j) o[j] = tile[sk + j][d];
      *reinterpret_cast<bf16x8*>(dst + (size_t)d * LK_ + sk) = o;
    }
  }
}

// ---------------- rowsum partials -> inverse rowsums ----------------
__global__ __launch_bounds__(256) void rowsum_inv_kernel(
    const float* __restrict__ pbuf, float* __restrict__ rinv) {
  int R = blockIdx.x * 256 + threadIdx.x;  // 0..16383
  int b = R >> 11, row = R & 2047;
  float s = 0.f;
#pragma unroll
  for (int cb = 0; cb < 8; ++cb)
    s += pbuf[((long)b * 8 + cb) * 2048 + row];
  rinv[R] = 1.0f / s;
}

// ------------ 256x256 8-phase GEMM, C = A * B^T, 32x32x16 MFMA ------------
// r15 + corrected swizzle. HW model (fit to r2/r3/r8/r11/r12/r15 counters):
// wave64 ds_read_b128 is serviced in stride-8 lane cohorts {r,r+8,..,r+56};
// conflict-free iff the 8 cohort lanes hit 8 distinct 16B granules.
// r15's q=row&7 gave 2 granules/cohort (+4 cy/read, 6.29M counts). New
// swizzle s(row) = ((row>>3)&3)<<1 (granule bits1-2 ^= row bits3-4):
// cohort granule = (2ks+g) ^ (jmod4)<<1 -> bit0=j>>2, bits12=ks^(j&3),
// 8 distinct. Involution both sides; rows+64/wr*128/wc*64 invariant.
//   A/B operand: row/col = lane&31, k = (lane>>5)*8 + j (8 bf16, b128 read)
//   C/D: col = lane&31, row = (reg&3) + 8*(reg>>2) + 4*(lane>>5)  [m74/m101]
// MODE 0: C bf16, C += bias[col]                    (Q projection)
// MODE 1: C bf16, C = exp(C/32 + mask[b][col]); + rowsum partials->extra2
// MODE 2: C f32,  C = acc * rinv[b][row]            (extra = rinv)
#define BARX __builtin_amdgcn_s_barrier()
#define PRIO1 __builtin_amdgcn_s_setprio(1)
#define PRIO0 __builtin_amdgcn_s_setprio(0)

#define RD_A2(MT, DOFF)                                                       \
  _Pragma("unroll") for (int ks = 0; ks < 4; ++ks) {                          \
    aF[0][ks] = *(const bf16x8*)(paks[ks] + (DOFF) + (MT) * 4096);            \
    aF[1][ks] = *(const bf16x8*)(paks[ks] + (DOFF) + ((MT) + 1) * 4096);      \
  }
#define RD_B(NT, DOFF, BF)                                                    \
  _Pragma("unroll") for (int ks = 0; ks < 4; ++ks)                            \
    BF[ks] = *(const bf16x8*)(pbks[ks] + (DOFF) + (NT) * 4096);
#define MQ8(MB, BF, NT)                                                       \
  _Pragma("unroll") for (int ks = 0; ks < 4; ++ks)                            \
  _Pragma("unroll") for (int m2 = 0; m2 < 2; ++m2)                            \
    acc[(MB) + m2][NT] = __builtin_amdgcn_mfma_f32_32x32x16_bf16(             \
        aF[m2][ks], BF[ks], acc[(MB) + m2][NT], 0, 0, 0);

template <int MODE>
__global__ __launch_bounds__(512, 1) void gemm_bt(
    const bf16_t* __restrict__ A, const bf16_t* __restrict__ Bm,
    void* __restrict__ Cv, const float* __restrict__ extra,
    float* __restrict__ extra2,
    int N, int K, long sA, long sB, long sC, long sE, int gxs, int gys) {
  __shared__ bf16_t lds[65536];  // A: d0 [0,32KB) d1 [32,64KB); B: [64,128KB)

  const int tid = threadIdx.x;
  const int lane = tid & 63;
  const int wave = tid >> 6;

  // XCD-aware bijective block swizzle (gridDim.x % 8 == 0 for all our grids)
  const int nwg = gridDim.x;
  const int lin = blockIdx.x;
  const int cpx = nwg >> 3;
  const int swz = (lin & 7) * cpx + (lin >> 3);
  const int gx = 1 << gxs;
  const int bx = swz & (gx - 1);
  const int rem = swz >> gxs;
  const int by = rem & ((1 << gys) - 1);
  const int bz = rem >> gys;

  const bf16_t* Ab = A + (long)bz * sA + (long)(by * 256) * K;
  const bf16_t* Bb = Bm + (long)bz * sB + (long)(bx * 256) * K;

  // staging geometry: row = tid>>3, phys granule = tid&7; source col is the
  // logical granule = phys ^ s(row), s(row) = ((row>>3)&3)<<1.
  const int r0 = tid >> 3;                                    // 0..63
  const int scol = ((tid & 7) ^ (((r0 >> 3) & 3) << 1)) * 8;  // pre-swizzled

  auto STG = [&](const bf16_t* Mb, int d, int mat, int h, int t) {
    const bf16_t* g = Mb + (long)(h * 128 + r0) * K + t * 64 + scol;
    bf16_t* l = lds + mat * 32768 + d * 16384 + h * 8192 + wave * 512;
    gload16(g, l);
    gload16(g + (long)64 * K, l + 4096);   // row+64: (row>>3)&3 unchanged
  };

  // fragment read geometry (32x32x16)
  const int wr = wave >> 2;   // 0..1
  const int wc = wave & 3;    // 0..3
  const int l31 = lane & 31;
  const int g = lane >> 5;    // k-group 0/1
  const int s2 = ((l31 >> 3) & 3) << 1;   // swizzle bits 1-2
  const char* ldsc = (const char*)lds;
  const char* paks[4];
  const char* pbks[4];
#pragma unroll
  for (int ks = 0; ks < 4; ++ks) {
    const int ga = ((ks * 2 + g) ^ s2) * 16;   // phys granule bytes
    paks[ks] = ldsc + (wr * 128 + l31) * 128 + ga;
    pbks[ks] = ldsc + 65536 + (wc * 64 + l31) * 128 + ga;
  }

  f32x16 acc[4][2] = {};
  bf16x8 aF[2][4], bF0[4], bF1[4];

  const int NT2 = K >> 7;  // iterations, 2 K-tiles (BK=64) each

  // prologue: t0 full (8 loads) + t1 B h0,h1 (4 loads)
  STG(Ab, 0, 0, 0, 0); STG(Ab, 0, 0, 1, 0);
  STG(Bb, 0, 1, 0, 0); STG(Bb, 0, 1, 1, 0);
  STG(Bb, 1, 1, 0, 1); STG(Bb, 1, 1, 1, 1);
  asm volatile("s_waitcnt vmcnt(4)" ::: "memory");  // t0 complete
  BARX;

  for (int j = 0; j < NT2; ++j) {
    const bool nl = (j + 1 < NT2);
    const int t1 = 2 * j + 1, t2 = 2 * j + 2, t3 = 2 * j + 3;
    // ---- P1: (m01, n0) of dbuf0 ----
    RD_A2(0, 0); RD_B(0, 0, bF0);
    STG(Ab, 1, 0, 0, t1);
    BARX; PRIO1; MQ8(0, bF0, 0); PRIO0; BARX;
    // ---- P2: (m01, n1) ----
    RD_B(1, 0, bF1);
    STG(Ab, 1, 0, 1, t1);
    BARX; PRIO1; MQ8(0, bF1, 1); PRIO0; BARX;
    // ---- P3: (m23, n1) ----
    RD_A2(2, 0);
    if (nl) STG(Bb, 0, 1, 0, t2);
    BARX; PRIO1; MQ8(2, bF1, 1); PRIO0; BARX;
    // ---- P4: (m23, n0); dbuf1 complete after this phase ----
    if (nl) STG(Bb, 0, 1, 1, t2);
    BARX; PRIO1; MQ8(2, bF0, 0); PRIO0;
    if (nl) { asm volatile("s_waitcnt vmcnt(4)" ::: "memory"); }
    else    { asm volatile("s_waitcnt vmcnt(0)" ::: "memory"); }
    BARX;
    // ---- P5: (m01, n0) of dbuf1 ----
    RD_A2(0, 32768); RD_B(0, 32768, bF0);
    if (nl) STG(Ab, 0, 0, 0, t2);
    BARX; PRIO1; MQ8(0, bF0, 0); PRIO0; BARX;
    // ---- P6: (m01, n1) ----
    RD_B(1, 32768, bF1);
    if (nl) STG(Ab, 0, 0, 1, t2);
    BARX; PRIO1; MQ8(0, bF1, 1); PRIO0; BARX;
    // ---- P7: (m23, n1) ----
    RD_A2(2, 32768);
    if (nl) STG(Bb, 1, 1, 0, t3);
    BARX; PRIO1; MQ8(2, bF1, 1); PRIO0; BARX;
    // ---- P8: (m23, n0); dbuf0 complete after this phase ----
    if (nl) STG(Bb, 1, 1, 1, t3);
    BARX; PRIO1; MQ8(2, bF0, 0); PRIO0;
    if (nl) { asm volatile("s_waitcnt vmcnt(4)" ::: "memory"); }
    BARX;
  }
  // loop exits with vmcnt==0 and all LDS reads complete -> LDS reusable.

  // epilogue (32x32 C/D layout)
  const int col0 = bx * 256 + wc * 64;
  const int row0 = by * 256 + wr * 128;

  if (MODE == 0) {
    bf16_t* C = (bf16_t*)Cv;
#pragma unroll
    for (int mt = 0; mt < 4; ++mt)
#pragma unroll
      for (int nt = 0; nt < 2; ++nt) {
        const int col = col0 + nt * 32 + l31;
        float bias = extra[col];
#pragma unroll
        for (int reg = 0; reg < 16; ++reg) {
          int row = row0 + mt * 32 + (reg & 3) + 8 * (reg >> 2) + 4 * g;
          C[(long)row * N + col] = (bf16_t)(acc[mt][nt][reg] + bias);
        }
      }
  } else if (MODE == 1) {
    bf16_t* C = (bf16_t*)Cv + (long)bz * sC;
    float* lds_f = (float*)lds;  // [wc][256 block-rows]
#pragma unroll
    for (int mt = 0; mt < 4; ++mt) {
      float s16[16];
#pragma unroll
      for (int r = 0; r < 16; ++r) s16[r] = 0.f;
#pragma unroll
      for (int nt = 0; nt < 2; ++nt) {
        const int col = col0 + nt * 32 + l31;
        float mk = extra[(long)bz * sE + col];
#pragma unroll
        for (int reg = 0; reg < 16; ++reg) {
          int row = row0 + mt * 32 + (reg & 3) + 8 * (reg >> 2) + 4 * g;
          float e = __expf(acc[mt][nt][reg] * 0.03125f + mk);
          C[(long)row * N + col] = (bf16_t)e;
          s16[reg] += e;
        }
      }
      // column-reduce over the 32 lanes of this half (xor<32 stays in-half)
#pragma unroll
      for (int reg = 0; reg < 16; ++reg) {
#pragma unroll
        for (int w = 1; w < 32; w <<= 1)
          s16[reg] += __shfl_xor(s16[reg], w, 64);
      }
      if (l31 == 0) {
#pragma unroll
        for (int reg = 0; reg < 16; ++reg) {
          int rl = (reg & 3) + 8 * (reg >> 2) + 4 * g;
          lds_f[wc * 256 + wr * 128 + mt * 32 + rl] = s16[reg];
        }
      }
    }
    __syncthreads();
    if (tid < 256) {
      float s4 = lds_f[tid] + lds_f[256 + tid] + lds_f[512 + tid] +
                 lds_f[768 + tid];
      extra2[((long)bz * 8 + bx) * 2048 + by * 256 + tid] = s4;
    }
  } else {
    float* C = (float*)Cv + (long)bz * sC;
    const float* rinv = extra + (long)bz * 2048;
#pragma unroll
    for (int mt = 0; mt < 4; ++mt)
#pragma unroll
      for (int reg = 0; reg < 16; ++reg) {
        int row = row0 + mt * 32 + (reg & 3) + 8 * (reg >> 2) + 4 * g;
        float iv = rinv[row];
#pragma unroll
        for (int nt = 0; nt < 2; ++nt) {
          const int col = col0 + nt * 32 + l31;
          C[(long)row * N + col] = acc[mt][nt][reg] * iv;
        }
      }
  }
}

extern "C" void kernel_launch(void* const* d_in, const int* in_sizes, int n_in,
                              void* d_out, int out_size, void* d_ws, size_t ws_size,
                              hipStream_t stream) {
  const float* x    = (const float*)d_in[0];
  const float* mask = (const float*)d_in[1];
  const float* keys = (const float*)d_in[2];
  const float* vals = (const float*)d_in[3];
  const float* Wq   = (const float*)d_in[4];
  const float* bq   = (const float*)d_in[5];
  float* out = (float*)d_out;

  char* ws = (char*)d_ws;
  bf16_t* kbf    = (bf16_t*)(ws);
  bf16_t* vt     = (bf16_t*)(ws + 33554432);
  bf16_t* qbf    = (bf16_t*)(ws + 67108864);
  bf16_t* logits = (bf16_t*)(ws + 100663296);  // holds p_unnorm = exp(logit)
  bf16_t* xbf    = logits;  // reused: x_bf dead before logits are written
  bf16_t* wqbf   = (bf16_t*)(ws + 167772160);
  float* pbuf = (float*)(ws + 167772160);            // [8][8][2048] partials
  float* rinv = (float*)(ws + 167772160 + 524288);   // [8][2048] 1/rowsum

  // 1. fused prep: converts + V transpose
  prep_kernel<<<6272, 256, 0, stream>>>(x, keys, Wq, vals, xbf, kbf, wqbf, vt);

  // 2. Q = x @ Wq^T + bq   (M=16384, N=1024, K=1024) grid 4x64 = 256
  gemm_bt<0><<<256, 512, 0, stream>>>(
      xbf, wqbf, qbf, bq, nullptr, DM_, DM_, 0, 0, 0, 0, 2, 6);

  // 3. p_unnorm = exp(Q @ K^T / 32 + mask), + rowsum partials
  gemm_bt<1><<<512, 512, 0, stream>>>(
      qbf, kbf, logits, mask, pbuf, LK_, DM_,
      (long)LQ_ * DM_, (long)LK_ * DM_, (long)LQ_ * LK_, LK_, 3, 3);

  // 4. rinv = 1 / rowsum
  rowsum_inv_kernel<<<64, 256, 0, stream>>>(pbuf, rinv);

  // 5. out = (P @ Vt^T) * rinv[row]  (per batch M=2048, N=1024, K=2048)
  gemm_bt<2><<<256, 512, 0, stream>>>(
      logits, vt, out, rinv, nullptr, DM_, LK_,
      (long)LQ_ * LK_, (long)DM_ * LK_, (long)LQ_ * DM_, 0, 2, 3);
}